// Round 5
// baseline (425.952 us; speedup 1.0000x reference)
//
#include <hip/hip_runtime.h>

#define NN 50000
#define EE 800000
#define IND 128
#define EDD 32
#define ODD 16
#define NH 4
#define HD 64
#define NEG_SLOPE 0.2f
#define NBLK ((NN + 255) / 256)   // 196 scan blocks

// ---------------- init: deg = 0 --------------------------------------------
__global__ __launch_bounds__(256)
void k_init(int* __restrict__ deg) {
    int i = blockIdx.x * 256 + threadIdx.x;
    if (i < NN) deg[i] = 0;
}

// ---------------- prep: Wt[k][j] = W_fc[j][k]; w_ee[h][k] folded -----------
__global__ __launch_bounds__(256)
void k_prep(const float* __restrict__ W_fc, const float* __restrict__ W_edge,
            const float* __restrict__ attn_e,
            float* __restrict__ Wt, float* __restrict__ w_ee) {
    int i = blockIdx.x * 256 + threadIdx.x;
    if (i < HD * IND) {
        int k = i >> 6, j = i & 63;
        Wt[i] = W_fc[j * IND + k];
    }
    if (i < NH * EDD) {
        int h = i >> 5, k = i & 31;
        float s = 0.f;
        for (int d = 0; d < ODD; ++d)
            s += W_edge[(h * ODD + d) * EDD + k] * attn_e[h * ODD + d];
        w_ee[i] = s;
    }
}

// ------- node projection (2 threads/node): feat_ = feat @ W_fc.T; eh2, et2 -
__global__ __launch_bounds__(256)
void k_node(const float* __restrict__ feat, const float* __restrict__ Wt,
            const float* __restrict__ attn_h, const float* __restrict__ attn_t,
            float* __restrict__ feat_ws, float2* __restrict__ eh2,
            float2* __restrict__ et2) {
    int t = blockIdx.x * 256 + threadIdx.x;
    int n = t >> 1, half = t & 1;           // j in [half*32, half*32+32)
    if (n >= NN) return;
    float acc[32];
#pragma unroll
    for (int j = 0; j < 32; ++j) acc[j] = 0.f;
    const float* fr = feat + (long)n * IND;
    const int jbase = half * 32;
#pragma unroll 1
    for (int k0 = 0; k0 < IND; k0 += 4) {
        float4 p = *(const float4*)(fr + k0);
        float f[4] = {p.x, p.y, p.z, p.w};
#pragma unroll
        for (int kk = 0; kk < 4; ++kk) {
            const float* w = Wt + (k0 + kk) * HD + jbase;  // wave-uniform -> s_load
#pragma unroll
            for (int j = 0; j < 32; ++j) acc[j] += f[kk] * w[j];
        }
    }
    float4* d4 = (float4*)(feat_ws + (long)n * HD + jbase);
#pragma unroll
    for (int q = 0; q < 8; ++q)
        d4[q] = make_float4(acc[q*4], acc[q*4+1], acc[q*4+2], acc[q*4+3]);
    // heads covered by this half: h = half*2 + hh, hh in {0,1}
    float sh[2], st[2];
#pragma unroll
    for (int hh = 0; hh < 2; ++hh) {
        sh[hh] = 0.f; st[hh] = 0.f;
        int hg = half * 2 + hh;
#pragma unroll
        for (int d = 0; d < ODD; ++d) {
            float av = acc[hh * ODD + d];
            sh[hh] += av * attn_h[hg * ODD + d];
            st[hh] += av * attn_t[hg * ODD + d];
        }
    }
    eh2[n * 2 + half] = make_float2(sh[0], sh[1]);
    et2[n * 2 + half] = make_float2(st[0], st[1]);
}

// ---------------- histogram of dst + per-edge rank --------------------------
__global__ __launch_bounds__(256)
void k_hist(const int* __restrict__ dst, int* __restrict__ deg, int* __restrict__ rank) {
    int e = blockIdx.x * 256 + threadIdx.x;
    if (e < EE) rank[e] = atomicAdd(&deg[dst[e]], 1);
}

// ---------------- two-level exclusive scan of deg -> offs -------------------
__global__ __launch_bounds__(256)
void k_scan1(const int* __restrict__ deg, int* __restrict__ offs, int* __restrict__ part) {
    __shared__ int s[256];
    int t = threadIdx.x, i = blockIdx.x * 256 + t;
    int v = (i < NN) ? deg[i] : 0;
    s[t] = v;
    __syncthreads();
#pragma unroll
    for (int o = 1; o < 256; o <<= 1) {
        int u = (t >= o) ? s[t - o] : 0;
        __syncthreads();
        if (t >= o) s[t] += u;
        __syncthreads();
    }
    if (i < NN) offs[i] = s[t] - v;
    if (t == 255) part[blockIdx.x] = s[255];
}

__global__ __launch_bounds__(256)
void k_scan2(int* __restrict__ part) {
    __shared__ int s[256];
    int t = threadIdx.x;
    int v = (t < NBLK) ? part[t] : 0;
    s[t] = v;
    __syncthreads();
#pragma unroll
    for (int o = 1; o < 256; o <<= 1) {
        int u = (t >= o) ? s[t - o] : 0;
        __syncthreads();
        if (t >= o) s[t] += u;
        __syncthreads();
    }
    if (t < NBLK) part[t] = s[t] - v;
}

__global__ __launch_bounds__(256)
void k_scan3(int* __restrict__ offs, const int* __restrict__ part) {
    int i = blockIdx.x * 256 + threadIdx.x;
    if (i < NN) offs[i] += part[i >> 8];
}

// ------- edge logits: a4 = exp(lrelu(eh[src]+ee+et[dst])), perm scatter ----
__global__ __launch_bounds__(256)
void k_logit(const float* __restrict__ edge_attr, const int* __restrict__ src,
             const int* __restrict__ dst, const float* __restrict__ w_ee,
             const float4* __restrict__ eh4, const float4* __restrict__ et4,
             const int* __restrict__ offs, const int* __restrict__ rank,
             float4* __restrict__ e_buf4, int* __restrict__ perm) {
    int e = blockIdx.x * 256 + threadIdx.x;
    if (e >= EE) return;
    int s_ = src[e], d_ = dst[e];
    int pos = offs[d_] + rank[e];           // no atomic
    float4 vh = eh4[s_];
    float4 vt = et4[d_];
    const float* ea = edge_attr + (long)e * EDD;
    float f[EDD];
#pragma unroll
    for (int c = 0; c < 8; ++c) {
        float4 p = *(const float4*)(ea + c * 4);
        f[c*4+0] = p.x; f[c*4+1] = p.y; f[c*4+2] = p.z; f[c*4+3] = p.w;
    }
    float x[NH];
#pragma unroll
    for (int h = 0; h < NH; ++h) {
        float s = 0.f;
#pragma unroll
        for (int k = 0; k < EDD; ++k) s += f[k] * w_ee[h * EDD + k];  // uniform -> s_load
        x[h] = s;
    }
    x[0] += vh.x + vt.x; x[1] += vh.y + vt.y;
    x[2] += vh.z + vt.z; x[3] += vh.w + vt.w;
#pragma unroll
    for (int h = 0; h < NH; ++h) {
        float v = x[h];
        v = v > 0.f ? v : NEG_SLOPE * v;
        x[h] = __expf(v);     // no max-shift: logits are 0.1-scale, fp32-safe
    }
    e_buf4[e] = make_float4(x[0], x[1], x[2], x[3]);  // coalesced write
    perm[pos] = e;                                    // only 4B scattered
}

// ------- per-dst reduce: chunked lane-parallel gather + shuffle broadcast ---
__global__ __launch_bounds__(256)
void k_reduce(const int* __restrict__ offs, const int* __restrict__ deg,
              const float* __restrict__ e_buf, const int* __restrict__ perm,
              const int* __restrict__ src, const float* __restrict__ feat_ws,
              const float* __restrict__ bias, float* __restrict__ out) {
    int wid = (blockIdx.x * 256 + threadIdx.x) >> 6;   // one wave per dst node
    int lane = threadIdx.x & 63;
    if (wid >= NN) return;
    int start = __builtin_amdgcn_readfirstlane(offs[wid]);
    int dn    = __builtin_amdgcn_readfirstlane(deg[wid]);
    int h = lane >> 4;          // head of this lane
    int q = lane & 15;          // edge slot within chunk
    float acc = 0.f, l = 0.f;

    for (int c0 = 0; c0 < dn; c0 += 16) {
        int rem = dn - c0; if (rem > 16) rem = 16;
        int qq = (q < rem) ? q : (rem - 1);            // clamp: stay in-bounds
        // lane-parallel gathers: lane l holds edge (l&15), head (l>>4)
        int   e_q = perm[start + c0 + qq];
        int   s_q = src[e_q];
        float a_q = (q < rem) ? e_buf[(long)e_q * 4 + h] : 0.f;
        // issue all feat row-gathers before consuming (16 loads in flight)
        float f[16];
#pragma unroll
        for (int i = 0; i < 16; ++i) {
            int si = __shfl(s_q, i);                   // edge i's src (from quad 0)
            f[i] = feat_ws[(long)si * HD + lane];      // coalesced 256B row gather
        }
#pragma unroll
        for (int i = 0; i < 16; ++i) {
            float ai = __shfl(a_q, (lane & 48) + i);   // edge i, this lane's head
            l += ai;
            acc += ai * f[i];
        }
    }
    float res = (l > 0.f) ? acc / l : 0.f;
    out[(long)wid * HD + lane] = res + bias[lane];
}

extern "C" void kernel_launch(void* const* d_in, const int* in_sizes, int n_in,
                              void* d_out, int out_size, void* d_ws, size_t ws_size,
                              hipStream_t stream) {
    const float* feat      = (const float*)d_in[0];
    const float* edge_attr = (const float*)d_in[1];
    const int*   src       = (const int*)d_in[2];
    const int*   dst       = (const int*)d_in[3];
    const float* W_fc      = (const float*)d_in[4];
    const float* W_edge    = (const float*)d_in[5];
    const float* attn_h    = (const float*)d_in[6];
    const float* attn_t    = (const float*)d_in[7];
    const float* attn_e    = (const float*)d_in[8];
    const float* bias      = (const float*)d_in[9];
    float* out             = (float*)d_out;

    float* ws        = (float*)d_ws;
    float4* e_buf4   = (float4*)ws;                    // E*4 floats
    float4* eh4      = e_buf4 + EE;                    // N*4
    float4* et4      = eh4 + NN;                       // N*4
    float*  feat_ws  = (float*)(et4 + NN);             // N*64
    float*  Wt       = feat_ws + (long)NN * HD;        // 8192
    float*  w_ee     = Wt + HD * IND;                  // 128
    int*    perm     = (int*)(w_ee + NH * EDD);        // E
    int*    rank     = perm + EE;                      // E
    int*    deg      = rank + EE;                      // N
    int*    offs     = deg + NN;                       // N
    int*    part     = offs + NN;                      // NBLK
    // total ~ 35 MB of d_ws

    k_init<<<NBLK, 256, 0, stream>>>(deg);
    k_prep<<<(HD * IND + 255) / 256, 256, 0, stream>>>(W_fc, W_edge, attn_e, Wt, w_ee);
    k_node<<<(NN * 2 + 255) / 256, 256, 0, stream>>>(feat, Wt, attn_h, attn_t, feat_ws,
                                                     (float2*)eh4, (float2*)et4);
    k_hist<<<(EE + 255) / 256, 256, 0, stream>>>(dst, deg, rank);
    k_scan1<<<NBLK, 256, 0, stream>>>(deg, offs, part);
    k_scan2<<<1, 256, 0, stream>>>(part);
    k_scan3<<<NBLK, 256, 0, stream>>>(offs, part);
    k_logit<<<(EE + 255) / 256, 256, 0, stream>>>(edge_attr, src, dst, w_ee, eh4, et4,
                                                  offs, rank, e_buf4, perm);
    k_reduce<<<(NN * 64 + 255) / 256, 256, 0, stream>>>(offs, deg, (const float*)e_buf4,
                                                        perm, src, feat_ws, bias, out);
}

// Round 6
// 350.085 us; speedup vs baseline: 1.2167x; 1.2167x over previous
//
#include <hip/hip_runtime.h>

#define NN 50000
#define EE 800000
#define IND 128
#define EDD 32
#define ODD 16
#define NH 4
#define HD 64
#define NEG_SLOPE 0.2f
#define NBLK ((NN + 255) / 256)   // 196 scan blocks

// ---------------- init: deg = 0 --------------------------------------------
__global__ __launch_bounds__(256)
void k_init(int* __restrict__ deg) {
    int i = blockIdx.x * 256 + threadIdx.x;
    if (i < NN) deg[i] = 0;
}

// ---------------- prep: Wt[k][j] = W_fc[j][k]; w_ee[h][k] folded -----------
__global__ __launch_bounds__(256)
void k_prep(const float* __restrict__ W_fc, const float* __restrict__ W_edge,
            const float* __restrict__ attn_e,
            float* __restrict__ Wt, float* __restrict__ w_ee) {
    int i = blockIdx.x * 256 + threadIdx.x;
    if (i < HD * IND) {
        int k = i >> 6, j = i & 63;
        Wt[i] = W_fc[j * IND + k];
    }
    if (i < NH * EDD) {
        int h = i >> 5, k = i & 31;
        float s = 0.f;
        for (int d = 0; d < ODD; ++d)
            s += W_edge[(h * ODD + d) * EDD + k] * attn_e[h * ODD + d];
        w_ee[i] = s;
    }
}

// ------- node projection: gridDim.y=2 halves; half is BLOCK-uniform so the
// ------- weight rows stay wave-uniform (s_load). Full feat row prefetched.
__global__ __launch_bounds__(256)
void k_node(const float* __restrict__ feat, const float* __restrict__ Wt,
            const float* __restrict__ attn_h, const float* __restrict__ attn_t,
            float* __restrict__ feat_ws, float2* __restrict__ eh2,
            float2* __restrict__ et2) {
    int n = blockIdx.x * 256 + threadIdx.x;
    int half = blockIdx.y;                  // block-uniform -> scalar weight loads
    if (n >= NN) return;
    const int jbase = half * 32;
    // prefetch entire feat row: 32 float4 loads in flight
    float4 row[32];
    const float4* fr4 = (const float4*)(feat + (long)n * IND);
#pragma unroll
    for (int q = 0; q < 32; ++q) row[q] = fr4[q];
    float acc[32];
#pragma unroll
    for (int j = 0; j < 32; ++j) acc[j] = 0.f;
#pragma unroll 4
    for (int k0 = 0; k0 < 32; ++k0) {
        float f[4] = {row[k0].x, row[k0].y, row[k0].z, row[k0].w};
#pragma unroll
        for (int kk = 0; kk < 4; ++kk) {
            const float* w = Wt + (k0 * 4 + kk) * HD + jbase;  // wave-uniform
#pragma unroll
            for (int j = 0; j < 32; ++j) acc[j] += f[kk] * w[j];
        }
    }
    float4* d4 = (float4*)(feat_ws + (long)n * HD + jbase);
#pragma unroll
    for (int q = 0; q < 8; ++q)
        d4[q] = make_float4(acc[q*4], acc[q*4+1], acc[q*4+2], acc[q*4+3]);
    // heads covered by this half: h = half*2 + hh, hh in {0,1}
    float sh[2], st[2];
#pragma unroll
    for (int hh = 0; hh < 2; ++hh) {
        sh[hh] = 0.f; st[hh] = 0.f;
        int hg = half * 2 + hh;
#pragma unroll
        for (int d = 0; d < ODD; ++d) {
            float av = acc[hh * ODD + d];
            sh[hh] += av * attn_h[hg * ODD + d];
            st[hh] += av * attn_t[hg * ODD + d];
        }
    }
    eh2[n * 2 + half] = make_float2(sh[0], sh[1]);
    et2[n * 2 + half] = make_float2(st[0], st[1]);
}

// ---------------- histogram of dst + per-edge rank --------------------------
__global__ __launch_bounds__(256)
void k_hist(const int* __restrict__ dst, int* __restrict__ deg, int* __restrict__ rank) {
    int e = blockIdx.x * 256 + threadIdx.x;
    if (e < EE) rank[e] = atomicAdd(&deg[dst[e]], 1);
}

// ---------------- two-level exclusive scan of deg -> offs -------------------
__global__ __launch_bounds__(256)
void k_scan1(const int* __restrict__ deg, int* __restrict__ offs, int* __restrict__ part) {
    __shared__ int s[256];
    int t = threadIdx.x, i = blockIdx.x * 256 + t;
    int v = (i < NN) ? deg[i] : 0;
    s[t] = v;
    __syncthreads();
#pragma unroll
    for (int o = 1; o < 256; o <<= 1) {
        int u = (t >= o) ? s[t - o] : 0;
        __syncthreads();
        if (t >= o) s[t] += u;
        __syncthreads();
    }
    if (i < NN) offs[i] = s[t] - v;
    if (t == 255) part[blockIdx.x] = s[255];
}

__global__ __launch_bounds__(256)
void k_scan2(int* __restrict__ part) {
    __shared__ int s[256];
    int t = threadIdx.x;
    int v = (t < NBLK) ? part[t] : 0;
    s[t] = v;
    __syncthreads();
#pragma unroll
    for (int o = 1; o < 256; o <<= 1) {
        int u = (t >= o) ? s[t - o] : 0;
        __syncthreads();
        if (t >= o) s[t] += u;
        __syncthreads();
    }
    if (t < NBLK) part[t] = s[t] - v;
}

__global__ __launch_bounds__(256)
void k_scan3(int* __restrict__ offs, const int* __restrict__ part) {
    int i = blockIdx.x * 256 + threadIdx.x;
    if (i < NN) offs[i] += part[i >> 8];
}

// ------- edge logits: a4 = exp(lrelu(eh[src]+ee+et[dst])), perm scatter ----
__global__ __launch_bounds__(256)
void k_logit(const float* __restrict__ edge_attr, const int* __restrict__ src,
             const int* __restrict__ dst, const float* __restrict__ w_ee,
             const float4* __restrict__ eh4, const float4* __restrict__ et4,
             const int* __restrict__ offs, const int* __restrict__ rank,
             float4* __restrict__ e_buf4, int* __restrict__ perm) {
    int e = blockIdx.x * 256 + threadIdx.x;
    if (e >= EE) return;
    int s_ = src[e], d_ = dst[e];
    int pos = offs[d_] + rank[e];           // no atomic
    float4 vh = eh4[s_];
    float4 vt = et4[d_];
    const float* ea = edge_attr + (long)e * EDD;
    float f[EDD];
#pragma unroll
    for (int c = 0; c < 8; ++c) {
        float4 p = *(const float4*)(ea + c * 4);
        f[c*4+0] = p.x; f[c*4+1] = p.y; f[c*4+2] = p.z; f[c*4+3] = p.w;
    }
    float x[NH];
#pragma unroll
    for (int h = 0; h < NH; ++h) {
        float s = 0.f;
#pragma unroll
        for (int k = 0; k < EDD; ++k) s += f[k] * w_ee[h * EDD + k];  // uniform -> s_load
        x[h] = s;
    }
    x[0] += vh.x + vt.x; x[1] += vh.y + vt.y;
    x[2] += vh.z + vt.z; x[3] += vh.w + vt.w;
#pragma unroll
    for (int h = 0; h < NH; ++h) {
        float v = x[h];
        v = v > 0.f ? v : NEG_SLOPE * v;
        x[h] = __expf(v);     // no max-shift: logits are 0.1-scale, fp32-safe
    }
    e_buf4[e] = make_float4(x[0], x[1], x[2], x[3]);  // coalesced write
    perm[pos] = e;                                    // only 4B scattered
}

// ------- per-dst reduce: chunked lane-parallel gather + shuffle broadcast ---
__global__ __launch_bounds__(256)
void k_reduce(const int* __restrict__ offs, const int* __restrict__ deg,
              const float* __restrict__ e_buf, const int* __restrict__ perm,
              const int* __restrict__ src, const float* __restrict__ feat_ws,
              const float* __restrict__ bias, float* __restrict__ out) {
    int wid = (blockIdx.x * 256 + threadIdx.x) >> 6;   // one wave per dst node
    int lane = threadIdx.x & 63;
    if (wid >= NN) return;
    int start = __builtin_amdgcn_readfirstlane(offs[wid]);
    int dn    = __builtin_amdgcn_readfirstlane(deg[wid]);
    int h = lane >> 4;          // head of this lane
    int q = lane & 15;          // edge slot within chunk
    float acc = 0.f, l = 0.f;

    for (int c0 = 0; c0 < dn; c0 += 16) {
        int rem = dn - c0; if (rem > 16) rem = 16;
        int qq = (q < rem) ? q : (rem - 1);            // clamp: stay in-bounds
        // lane-parallel gathers: lane l holds edge (l&15), head (l>>4)
        int   e_q = perm[start + c0 + qq];
        int   s_q = src[e_q];
        float a_q = (q < rem) ? e_buf[(long)e_q * 4 + h] : 0.f;
        // issue all feat row-gathers before consuming (16 loads in flight)
        float f[16];
#pragma unroll
        for (int i = 0; i < 16; ++i) {
            int si = __shfl(s_q, i);                   // edge i's src (from quad 0)
            f[i] = feat_ws[(long)si * HD + lane];      // coalesced 256B row gather
        }
#pragma unroll
        for (int i = 0; i < 16; ++i) {
            float ai = __shfl(a_q, (lane & 48) + i);   // edge i, this lane's head
            l += ai;
            acc += ai * f[i];
        }
    }
    float res = (l > 0.f) ? acc / l : 0.f;
    out[(long)wid * HD + lane] = res + bias[lane];
}

extern "C" void kernel_launch(void* const* d_in, const int* in_sizes, int n_in,
                              void* d_out, int out_size, void* d_ws, size_t ws_size,
                              hipStream_t stream) {
    const float* feat      = (const float*)d_in[0];
    const float* edge_attr = (const float*)d_in[1];
    const int*   src       = (const int*)d_in[2];
    const int*   dst       = (const int*)d_in[3];
    const float* W_fc      = (const float*)d_in[4];
    const float* W_edge    = (const float*)d_in[5];
    const float* attn_h    = (const float*)d_in[6];
    const float* attn_t    = (const float*)d_in[7];
    const float* attn_e    = (const float*)d_in[8];
    const float* bias      = (const float*)d_in[9];
    float* out             = (float*)d_out;

    float* ws        = (float*)d_ws;
    float4* e_buf4   = (float4*)ws;                    // E*4 floats
    float4* eh4      = e_buf4 + EE;                    // N*4
    float4* et4      = eh4 + NN;                       // N*4
    float*  feat_ws  = (float*)(et4 + NN);             // N*64
    float*  Wt       = feat_ws + (long)NN * HD;        // 8192
    float*  w_ee     = Wt + HD * IND;                  // 128
    int*    perm     = (int*)(w_ee + NH * EDD);        // E
    int*    rank     = perm + EE;                      // E
    int*    deg      = rank + EE;                      // N
    int*    offs     = deg + NN;                       // N
    int*    part     = offs + NN;                      // NBLK
    // total ~ 35 MB of d_ws

    k_init<<<NBLK, 256, 0, stream>>>(deg);
    k_prep<<<(HD * IND + 255) / 256, 256, 0, stream>>>(W_fc, W_edge, attn_e, Wt, w_ee);
    dim3 ngrid(NBLK, 2);
    k_node<<<ngrid, 256, 0, stream>>>(feat, Wt, attn_h, attn_t, feat_ws,
                                      (float2*)eh4, (float2*)et4);
    k_hist<<<(EE + 255) / 256, 256, 0, stream>>>(dst, deg, rank);
    k_scan1<<<NBLK, 256, 0, stream>>>(deg, offs, part);
    k_scan2<<<1, 256, 0, stream>>>(part);
    k_scan3<<<NBLK, 256, 0, stream>>>(offs, part);
    k_logit<<<(EE + 255) / 256, 256, 0, stream>>>(edge_attr, src, dst, w_ee, eh4, et4,
                                                  offs, rank, e_buf4, perm);
    k_reduce<<<(NN * 64 + 255) / 256, 256, 0, stream>>>(offs, deg, (const float*)e_buf4,
                                                        perm, src, feat_ws, bias, out);
}

// Round 7
// 340.696 us; speedup vs baseline: 1.2502x; 1.0276x over previous
//
#include <hip/hip_runtime.h>

#define NN 50000
#define EE 800000
#define IND 128
#define EDD 32
#define ODD 16
#define NH 4
#define HD 64
#define NEG_SLOPE 0.2f
#define NBLK ((NN + 255) / 256)   // 196 scan blocks

// ---------------- init: deg = 0 --------------------------------------------
__global__ __launch_bounds__(256)
void k_init(int* __restrict__ deg) {
    int i = blockIdx.x * 256 + threadIdx.x;
    if (i < NN) deg[i] = 0;
}

// ---------------- prep: Wt[k][j] = W_fc[j][k]; w_ee[h][k] folded -----------
__global__ __launch_bounds__(256)
void k_prep(const float* __restrict__ W_fc, const float* __restrict__ W_edge,
            const float* __restrict__ attn_e,
            float* __restrict__ Wt, float* __restrict__ w_ee) {
    int i = blockIdx.x * 256 + threadIdx.x;
    if (i < HD * IND) {
        int k = i >> 6, j = i & 63;
        Wt[i] = W_fc[j * IND + k];
    }
    if (i < NH * EDD) {
        int h = i >> 5, k = i & 31;
        float s = 0.f;
        for (int d = 0; d < ODD; ++d)
            s += W_edge[(h * ODD + d) * EDD + k] * attn_e[h * ODD + d];
        w_ee[i] = s;
    }
}

// ------- node projection: gridDim.y=2 halves (block-uniform -> s_load weights)
// ------- full feat row prefetched; barrier keeps all 32 loads in flight.
__global__ __launch_bounds__(256)
void k_node(const float* __restrict__ feat, const float* __restrict__ Wt,
            const float* __restrict__ attn_h, const float* __restrict__ attn_t,
            float* __restrict__ feat_ws, float2* __restrict__ eh2,
            float2* __restrict__ et2) {
    int n = blockIdx.x * 256 + threadIdx.x;
    int half = blockIdx.y;                  // block-uniform -> scalar weight loads
    if (n >= NN) return;
    const int jbase = half * 32;
    // prefetch entire feat row: 32 float4 loads in flight
    float4 row[32];
    const float4* fr4 = (const float4*)(feat + (long)n * IND);
#pragma unroll
    for (int q = 0; q < 32; ++q) row[q] = fr4[q];
    asm volatile("" ::: "memory");          // keep the loads hoisted (VGPR is free here)
    float acc[32];
#pragma unroll
    for (int j = 0; j < 32; ++j) acc[j] = 0.f;
#pragma unroll
    for (int k0 = 0; k0 < 32; ++k0) {
        float f[4] = {row[k0].x, row[k0].y, row[k0].z, row[k0].w};
#pragma unroll
        for (int kk = 0; kk < 4; ++kk) {
            const float* w = Wt + (k0 * 4 + kk) * HD + jbase;  // wave-uniform
#pragma unroll
            for (int j = 0; j < 32; ++j) acc[j] += f[kk] * w[j];
        }
    }
    float4* d4 = (float4*)(feat_ws + (long)n * HD + jbase);
#pragma unroll
    for (int q = 0; q < 8; ++q)
        d4[q] = make_float4(acc[q*4], acc[q*4+1], acc[q*4+2], acc[q*4+3]);
    // heads covered by this half: h = half*2 + hh, hh in {0,1}
    float sh[2], st[2];
#pragma unroll
    for (int hh = 0; hh < 2; ++hh) {
        sh[hh] = 0.f; st[hh] = 0.f;
        int hg = half * 2 + hh;
#pragma unroll
        for (int d = 0; d < ODD; ++d) {
            float av = acc[hh * ODD + d];
            sh[hh] += av * attn_h[hg * ODD + d];
            st[hh] += av * attn_t[hg * ODD + d];
        }
    }
    eh2[n * 2 + half] = make_float2(sh[0], sh[1]);
    et2[n * 2 + half] = make_float2(st[0], st[1]);
}

// ---------------- histogram of dst + per-edge rank --------------------------
__global__ __launch_bounds__(256)
void k_hist(const int* __restrict__ dst, int* __restrict__ deg, int* __restrict__ rank) {
    int e = blockIdx.x * 256 + threadIdx.x;
    if (e < EE) rank[e] = atomicAdd(&deg[dst[e]], 1);
}

// ---------------- two-level exclusive scan of deg -> offs -------------------
__global__ __launch_bounds__(256)
void k_scan1(const int* __restrict__ deg, int* __restrict__ offs, int* __restrict__ part) {
    __shared__ int s[256];
    int t = threadIdx.x, i = blockIdx.x * 256 + t;
    int v = (i < NN) ? deg[i] : 0;
    s[t] = v;
    __syncthreads();
#pragma unroll
    for (int o = 1; o < 256; o <<= 1) {
        int u = (t >= o) ? s[t - o] : 0;
        __syncthreads();
        if (t >= o) s[t] += u;
        __syncthreads();
    }
    if (i < NN) offs[i] = s[t] - v;
    if (t == 255) part[blockIdx.x] = s[255];
}

__global__ __launch_bounds__(256)
void k_scan2(int* __restrict__ part) {
    __shared__ int s[256];
    int t = threadIdx.x;
    int v = (t < NBLK) ? part[t] : 0;
    s[t] = v;
    __syncthreads();
#pragma unroll
    for (int o = 1; o < 256; o <<= 1) {
        int u = (t >= o) ? s[t - o] : 0;
        __syncthreads();
        if (t >= o) s[t] += u;
        __syncthreads();
    }
    if (t < NBLK) part[t] = s[t] - v;
}

__global__ __launch_bounds__(256)
void k_scan3(int* __restrict__ offs, const int* __restrict__ part) {
    int i = blockIdx.x * 256 + threadIdx.x;
    if (i < NN) offs[i] += part[i >> 8];
}

// ------- edge logits (2 edges/thread): a4 = exp(lrelu(eh[src]+ee+et[dst])) --
__global__ __launch_bounds__(256)
void k_logit(const float* __restrict__ edge_attr, const int* __restrict__ src,
             const int* __restrict__ dst, const float* __restrict__ w_ee,
             const float4* __restrict__ eh4, const float4* __restrict__ et4,
             const int* __restrict__ offs, const int* __restrict__ rank,
             float4* __restrict__ e_buf4, int* __restrict__ perm) {
    int t = blockIdx.x * 256 + threadIdx.x;
    int e0 = t * 2;
    if (e0 >= EE) return;
    // coalesced pair loads + all gathers issued up-front
    int2 s2 = *(const int2*)(src + e0);
    int2 d2 = *(const int2*)(dst + e0);
    int2 r2 = *(const int2*)(rank + e0);
    int   o0 = offs[d2.x], o1 = offs[d2.y];
    float4 vh0 = eh4[s2.x], vh1 = eh4[s2.y];
    float4 vt0 = et4[d2.x], vt1 = et4[d2.y];
    const float4* ea = (const float4*)(edge_attr + (long)e0 * EDD);
    float4 r[16];
#pragma unroll
    for (int c = 0; c < 16; ++c) r[c] = ea[c];
    asm volatile("" ::: "memory");
    const float* f0 = (const float*)&r[0];
    const float* f1 = (const float*)&r[8];
    float x0[NH], x1[NH];
#pragma unroll
    for (int h = 0; h < NH; ++h) {
        float a = 0.f, b = 0.f;
#pragma unroll
        for (int k = 0; k < EDD; ++k) {
            float w = w_ee[h * EDD + k];    // uniform -> s_load
            a += f0[k] * w;
            b += f1[k] * w;
        }
        x0[h] = a; x1[h] = b;
    }
    x0[0] += vh0.x + vt0.x; x0[1] += vh0.y + vt0.y;
    x0[2] += vh0.z + vt0.z; x0[3] += vh0.w + vt0.w;
    x1[0] += vh1.x + vt1.x; x1[1] += vh1.y + vt1.y;
    x1[2] += vh1.z + vt1.z; x1[3] += vh1.w + vt1.w;
#pragma unroll
    for (int h = 0; h < NH; ++h) {
        float v0 = x0[h], v1 = x1[h];
        v0 = v0 > 0.f ? v0 : NEG_SLOPE * v0;
        v1 = v1 > 0.f ? v1 : NEG_SLOPE * v1;
        x0[h] = __expf(v0);   // no max-shift: logits are 0.1-scale, fp32-safe
        x1[h] = __expf(v1);
    }
    e_buf4[e0]     = make_float4(x0[0], x0[1], x0[2], x0[3]);  // coalesced
    e_buf4[e0 + 1] = make_float4(x1[0], x1[1], x1[2], x1[3]);
    perm[o0 + r2.x] = e0;                                      // 4B scatters
    perm[o1 + r2.y] = e0 + 1;
}

// ------- per-dst reduce: chunked lane-parallel gather + shuffle broadcast ---
__global__ __launch_bounds__(256)
void k_reduce(const int* __restrict__ offs, const int* __restrict__ deg,
              const float* __restrict__ e_buf, const int* __restrict__ perm,
              const int* __restrict__ src, const float* __restrict__ feat_ws,
              const float* __restrict__ bias, float* __restrict__ out) {
    int wid = (blockIdx.x * 256 + threadIdx.x) >> 6;   // one wave per dst node
    int lane = threadIdx.x & 63;
    if (wid >= NN) return;
    int start = __builtin_amdgcn_readfirstlane(offs[wid]);
    int dn    = __builtin_amdgcn_readfirstlane(deg[wid]);
    int h = lane >> 4;          // head of this lane
    int q = lane & 15;          // edge slot within chunk
    float acc = 0.f, l = 0.f;

    for (int c0 = 0; c0 < dn; c0 += 16) {
        int rem = dn - c0; if (rem > 16) rem = 16;
        int qq = (q < rem) ? q : (rem - 1);            // clamp: stay in-bounds
        int   e_q = perm[start + c0 + qq];
        int   s_q = src[e_q];
        float a_q = (q < rem) ? e_buf[(long)e_q * 4 + h] : 0.f;
        float f[16];
#pragma unroll
        for (int i = 0; i < 16; ++i) {
            int si = __shfl(s_q, i);                   // edge i's src (quad 0)
            f[i] = feat_ws[(long)si * HD + lane];      // coalesced 256B row gather
        }
#pragma unroll
        for (int i = 0; i < 16; ++i) {
            float ai = __shfl(a_q, (lane & 48) + i);   // edge i, this lane's head
            l += ai;
            acc += ai * f[i];
        }
    }
    float res = (l > 0.f) ? acc / l : 0.f;
    out[(long)wid * HD + lane] = res + bias[lane];
}

extern "C" void kernel_launch(void* const* d_in, const int* in_sizes, int n_in,
                              void* d_out, int out_size, void* d_ws, size_t ws_size,
                              hipStream_t stream) {
    const float* feat      = (const float*)d_in[0];
    const float* edge_attr = (const float*)d_in[1];
    const int*   src       = (const int*)d_in[2];
    const int*   dst       = (const int*)d_in[3];
    const float* W_fc      = (const float*)d_in[4];
    const float* W_edge    = (const float*)d_in[5];
    const float* attn_h    = (const float*)d_in[6];
    const float* attn_t    = (const float*)d_in[7];
    const float* attn_e    = (const float*)d_in[8];
    const float* bias      = (const float*)d_in[9];
    float* out             = (float*)d_out;

    float* ws        = (float*)d_ws;
    float4* e_buf4   = (float4*)ws;                    // E*4 floats
    float4* eh4      = e_buf4 + EE;                    // N*4
    float4* et4      = eh4 + NN;                       // N*4
    float*  feat_ws  = (float*)(et4 + NN);             // N*64
    float*  Wt       = feat_ws + (long)NN * HD;        // 8192
    float*  w_ee     = Wt + HD * IND;                  // 128
    int*    perm     = (int*)(w_ee + NH * EDD);        // E
    int*    rank     = perm + EE;                      // E
    int*    deg      = rank + EE;                      // N
    int*    offs     = deg + NN;                       // N
    int*    part     = offs + NN;                      // NBLK
    // total ~ 35 MB of d_ws

    k_init<<<NBLK, 256, 0, stream>>>(deg);
    k_prep<<<(HD * IND + 255) / 256, 256, 0, stream>>>(W_fc, W_edge, attn_e, Wt, w_ee);
    dim3 ngrid(NBLK, 2);
    k_node<<<ngrid, 256, 0, stream>>>(feat, Wt, attn_h, attn_t, feat_ws,
                                      (float2*)eh4, (float2*)et4);
    k_hist<<<(EE + 255) / 256, 256, 0, stream>>>(dst, deg, rank);
    k_scan1<<<NBLK, 256, 0, stream>>>(deg, offs, part);
    k_scan2<<<1, 256, 0, stream>>>(part);
    k_scan3<<<NBLK, 256, 0, stream>>>(offs, part);
    k_logit<<<(EE / 2 + 255) / 256, 256, 0, stream>>>(edge_attr, src, dst, w_ee, eh4, et4,
                                                      offs, rank, e_buf4, perm);
    k_reduce<<<(NN * 64 + 255) / 256, 256, 0, stream>>>(offs, deg, (const float*)e_buf4,
                                                        perm, src, feat_ws, bias, out);
}

// Round 8
// 334.614 us; speedup vs baseline: 1.2730x; 1.0182x over previous
//
#include <hip/hip_runtime.h>

#define NN 50000
#define EE 800000
#define IND 128
#define EDD 32
#define ODD 16
#define NH 4
#define HD 64
#define NEG_SLOPE 0.2f
#define NBLK ((NN + 255) / 256)   // 196 scan blocks

// ---------------- init+prep fused: deg=0; Wt transpose; w_ee fold ----------
__global__ __launch_bounds__(256)
void k_init_prep(int* __restrict__ deg, const float* __restrict__ W_fc,
                 const float* __restrict__ W_edge, const float* __restrict__ attn_e,
                 float* __restrict__ Wt, float* __restrict__ w_ee) {
    int i = blockIdx.x * 256 + threadIdx.x;
    if (i < NN) deg[i] = 0;
    if (i < HD * IND) {
        int k = i >> 6, j = i & 63;
        Wt[i] = W_fc[j * IND + k];
    }
    if (i < NH * EDD) {
        int h = i >> 5, k = i & 31;
        float s = 0.f;
        for (int d = 0; d < ODD; ++d)
            s += W_edge[(h * ODD + d) * EDD + k] * attn_e[h * ODD + d];
        w_ee[i] = s;
    }
}

// ------- node projection: gridDim.y=2 halves (block-uniform -> s_load weights)
// ------- full feat row prefetched; barrier keeps all 32 loads in flight.
__global__ __launch_bounds__(256)
void k_node(const float* __restrict__ feat, const float* __restrict__ Wt,
            const float* __restrict__ attn_h, const float* __restrict__ attn_t,
            float* __restrict__ feat_ws, float2* __restrict__ eh2,
            float2* __restrict__ et2) {
    int n = blockIdx.x * 256 + threadIdx.x;
    int half = blockIdx.y;                  // block-uniform -> scalar weight loads
    if (n >= NN) return;
    const int jbase = half * 32;
    float4 row[32];
    const float4* fr4 = (const float4*)(feat + (long)n * IND);
#pragma unroll
    for (int q = 0; q < 32; ++q) row[q] = fr4[q];
    asm volatile("" ::: "memory");          // keep all 32 loads hoisted
    float acc[32];
#pragma unroll
    for (int j = 0; j < 32; ++j) acc[j] = 0.f;
#pragma unroll
    for (int k0 = 0; k0 < 32; ++k0) {
        float f[4] = {row[k0].x, row[k0].y, row[k0].z, row[k0].w};
#pragma unroll
        for (int kk = 0; kk < 4; ++kk) {
            const float* w = Wt + (k0 * 4 + kk) * HD + jbase;  // wave-uniform
#pragma unroll
            for (int j = 0; j < 32; ++j) acc[j] += f[kk] * w[j];
        }
    }
    float4* d4 = (float4*)(feat_ws + (long)n * HD + jbase);
#pragma unroll
    for (int q = 0; q < 8; ++q)
        d4[q] = make_float4(acc[q*4], acc[q*4+1], acc[q*4+2], acc[q*4+3]);
    float sh[2], st[2];
#pragma unroll
    for (int hh = 0; hh < 2; ++hh) {
        sh[hh] = 0.f; st[hh] = 0.f;
        int hg = half * 2 + hh;
#pragma unroll
        for (int d = 0; d < ODD; ++d) {
            float av = acc[hh * ODD + d];
            sh[hh] += av * attn_h[hg * ODD + d];
            st[hh] += av * attn_t[hg * ODD + d];
        }
    }
    eh2[n * 2 + half] = make_float2(sh[0], sh[1]);
    et2[n * 2 + half] = make_float2(st[0], st[1]);
}

// ---------------- histogram of dst + per-edge rank --------------------------
__global__ __launch_bounds__(256)
void k_hist(const int* __restrict__ dst, int* __restrict__ deg, int* __restrict__ rank) {
    int e = blockIdx.x * 256 + threadIdx.x;
    if (e < EE) rank[e] = atomicAdd(&deg[dst[e]], 1);
}

// ---------------- two-level exclusive scan of deg -> offs -------------------
__global__ __launch_bounds__(256)
void k_scan1(const int* __restrict__ deg, int* __restrict__ offs, int* __restrict__ part) {
    __shared__ int s[256];
    int t = threadIdx.x, i = blockIdx.x * 256 + t;
    int v = (i < NN) ? deg[i] : 0;
    s[t] = v;
    __syncthreads();
#pragma unroll
    for (int o = 1; o < 256; o <<= 1) {
        int u = (t >= o) ? s[t - o] : 0;
        __syncthreads();
        if (t >= o) s[t] += u;
        __syncthreads();
    }
    if (i < NN) offs[i] = s[t] - v;
    if (t == 255) part[blockIdx.x] = s[255];
}

__global__ __launch_bounds__(256)
void k_scan2(int* __restrict__ part) {
    __shared__ int s[256];
    int t = threadIdx.x;
    int v = (t < NBLK) ? part[t] : 0;
    s[t] = v;
    __syncthreads();
#pragma unroll
    for (int o = 1; o < 256; o <<= 1) {
        int u = (t >= o) ? s[t - o] : 0;
        __syncthreads();
        if (t >= o) s[t] += u;
        __syncthreads();
    }
    if (t < NBLK) part[t] = s[t] - v;
}

__global__ __launch_bounds__(256)
void k_scan3(int* __restrict__ offs, const int* __restrict__ part) {
    int i = blockIdx.x * 256 + threadIdx.x;
    if (i < NN) offs[i] += part[i >> 8];
}

// ------- edge MLP (2 edges/thread): ee4[e] = edge_attr@w_ee.T; perm scatter -
// ------- no src/eh/et gathers, no exp: pure streaming + dst->pos scatter ----
__global__ __launch_bounds__(256)
void k_logit2(const float* __restrict__ edge_attr, const int* __restrict__ dst,
              const float* __restrict__ w_ee, const int* __restrict__ offs,
              const int* __restrict__ rank, float4* __restrict__ ee4,
              int* __restrict__ perm) {
    int t = blockIdx.x * 256 + threadIdx.x;
    int e0 = t * 2;
    if (e0 >= EE) return;
    int2 d2 = *(const int2*)(dst + e0);
    int2 r2 = *(const int2*)(rank + e0);
    int   o0 = offs[d2.x], o1 = offs[d2.y];
    const float4* ea = (const float4*)(edge_attr + (long)e0 * EDD);
    float4 r[16];
#pragma unroll
    for (int c = 0; c < 16; ++c) r[c] = ea[c];
    asm volatile("" ::: "memory");
    const float* f0 = (const float*)&r[0];
    const float* f1 = (const float*)&r[8];
    float x0[NH], x1[NH];
#pragma unroll
    for (int h = 0; h < NH; ++h) {
        float a = 0.f, b = 0.f;
#pragma unroll
        for (int k = 0; k < EDD; ++k) {
            float w = w_ee[h * EDD + k];    // uniform -> s_load
            a += f0[k] * w;
            b += f1[k] * w;
        }
        x0[h] = a; x1[h] = b;
    }
    ee4[e0]     = make_float4(x0[0], x0[1], x0[2], x0[3]);   // coalesced
    ee4[e0 + 1] = make_float4(x1[0], x1[1], x1[2], x1[3]);
    perm[o0 + r2.x] = e0;                                    // 4B scatters
    perm[o1 + r2.y] = e0 + 1;
}

// ------- per-dst reduce: logit assembly + softmax + weighted gather ---------
__global__ __launch_bounds__(256)
void k_reduce(const int* __restrict__ offs, const int* __restrict__ deg,
              const float* __restrict__ ee, const float* __restrict__ eh,
              const float* __restrict__ et, const int* __restrict__ perm,
              const int* __restrict__ src, const float* __restrict__ feat_ws,
              const float* __restrict__ bias, float* __restrict__ out) {
    int wid = (blockIdx.x * 256 + threadIdx.x) >> 6;   // one wave per dst node
    int lane = threadIdx.x & 63;
    if (wid >= NN) return;
    int start = __builtin_amdgcn_readfirstlane(offs[wid]);
    int dn    = __builtin_amdgcn_readfirstlane(deg[wid]);
    int h = lane >> 4;          // head of this lane
    int q = lane & 15;          // edge slot within chunk
    float et_h = et[(long)wid * 4 + h];                // wave-level uniform (1 line)
    float acc = 0.f, l = 0.f;

    for (int c0 = 0; c0 < dn; c0 += 16) {
        int rem = dn - c0; if (rem > 16) rem = 16;
        int qq = (q < rem) ? q : (rem - 1);            // clamp: stay in-bounds
        int   e_q = perm[start + c0 + qq];             // 1 line per wave
        int   s_q = src[e_q];                          // random 4B gather
        float ee_q = ee[(long)e_q * 4 + h];            // random 4B gather (L3-hot)
        float eh_q = eh[(long)s_q * 4 + h];            // random 4B gather (L2-hot)
        float x = ee_q + eh_q + et_h;
        x = x > 0.f ? x : NEG_SLOPE * x;
        float a_q = (q < rem) ? __expf(x) : 0.f;       // no max-shift: 0.1-scale logits
        float f[16];
#pragma unroll
        for (int i = 0; i < 16; ++i) {
            int si = __shfl(s_q, i);                   // edge i's src (quad 0)
            f[i] = feat_ws[(long)si * HD + lane];      // coalesced 256B row gather
        }
#pragma unroll
        for (int i = 0; i < 16; ++i) {
            float ai = __shfl(a_q, (lane & 48) + i);   // edge i, this lane's head
            l += ai;
            acc += ai * f[i];
        }
    }
    float res = (l > 0.f) ? acc / l : 0.f;
    out[(long)wid * HD + lane] = res + bias[lane];
}

extern "C" void kernel_launch(void* const* d_in, const int* in_sizes, int n_in,
                              void* d_out, int out_size, void* d_ws, size_t ws_size,
                              hipStream_t stream) {
    const float* feat      = (const float*)d_in[0];
    const float* edge_attr = (const float*)d_in[1];
    const int*   src       = (const int*)d_in[2];
    const int*   dst       = (const int*)d_in[3];
    const float* W_fc      = (const float*)d_in[4];
    const float* W_edge    = (const float*)d_in[5];
    const float* attn_h    = (const float*)d_in[6];
    const float* attn_t    = (const float*)d_in[7];
    const float* attn_e    = (const float*)d_in[8];
    const float* bias      = (const float*)d_in[9];
    float* out             = (float*)d_out;

    float* ws        = (float*)d_ws;
    float4* ee4      = (float4*)ws;                    // E*4 floats
    float4* eh4      = ee4 + EE;                       // N*4
    float4* et4      = eh4 + NN;                       // N*4
    float*  feat_ws  = (float*)(et4 + NN);             // N*64
    float*  Wt       = feat_ws + (long)NN * HD;        // 8192
    float*  w_ee     = Wt + HD * IND;                  // 128
    int*    perm     = (int*)(w_ee + NH * EDD);        // E
    int*    rank     = perm + EE;                      // E
    int*    deg      = rank + EE;                      // N
    int*    offs     = deg + NN;                       // N
    int*    part     = offs + NN;                      // NBLK
    // total ~ 35 MB of d_ws

    k_init_prep<<<NBLK, 256, 0, stream>>>(deg, W_fc, W_edge, attn_e, Wt, w_ee);
    dim3 ngrid(NBLK, 2);
    k_node<<<ngrid, 256, 0, stream>>>(feat, Wt, attn_h, attn_t, feat_ws,
                                      (float2*)eh4, (float2*)et4);
    k_hist<<<(EE + 255) / 256, 256, 0, stream>>>(dst, deg, rank);
    k_scan1<<<NBLK, 256, 0, stream>>>(deg, offs, part);
    k_scan2<<<1, 256, 0, stream>>>(part);
    k_scan3<<<NBLK, 256, 0, stream>>>(offs, part);
    k_logit2<<<(EE / 2 + 255) / 256, 256, 0, stream>>>(edge_attr, dst, w_ee, offs, rank,
                                                       ee4, perm);
    k_reduce<<<(NN * 64 + 255) / 256, 256, 0, stream>>>(offs, deg, (const float*)ee4,
                                                        (const float*)eh4, (const float*)et4,
                                                        perm, src, feat_ws, bias, out);
}